// Round 6
// baseline (171.188 us; speedup 1.0000x reference)
//
#include <hip/hip_runtime.h>
#include <math.h>

#define HEADS 8
#define DK 32
#define B_ 4
#define C_ 256
#define NVOX 1728   // 12*12*12
#define DE 64       // effective head dim: Q'=[q;pos], K'=[k;q]
#define XP32 66     // fproj fp32 x-tile pitch (floats): 264B rows, float2-aligned
#define CPITCH 36   // fproj cbuf pitch (floats)
#define LOG2E 1.44269504088896f
#define JSPLIT 3    // j-dimension split (27 = 3*9 tiles)
#define NJT 9       // j-tiles per block
#define ITILES 14   // ceil(1728/128) i-tiles (tail masked)

typedef _Float16 f16x8 __attribute__((ext_vector_type(8)));
typedef __fp16 fp16x2 __attribute__((ext_vector_type(2)));
typedef float f32x16 __attribute__((ext_vector_type(16)));

__device__ inline float h2f(short s) {
    _Float16 h = *(_Float16*)&s;
    return (float)h;
}
__device__ inline f32x16 mfma32h(f16x8 a, f16x8 b, f32x16 c) {
    return __builtin_amdgcn_mfma_f32_32x32x16_f16(a, b, c, 0, 0, 0);
}
// async global->LDS DMA, 16B per lane; LDS dest = wave-uniform base + lane*16
__device__ __forceinline__ void gl_lds16(const short* g, short* l) {
    __builtin_amdgcn_global_load_lds(
        (const __attribute__((address_space(1))) unsigned int*)g,
        (__attribute__((address_space(3))) unsigned int*)l, 16, 0, 0);
}

union H8 { _Float16 h[8]; uint4 v; };
union PW { fp16x2 h2; unsigned int u; };

// ---------------------------------------------------------------------------
// Fused projection (prep merged in):
//  - reads x fp32 directly, transposes via LDS [c][n] fp32 tile (pitch 66)
//  - converts weights fp32->f16 at A-frag load (L2-resident, 108x reuse)
//  - computes pos -> Qf upper half in prologue (overlaps staging)
//  grid (27, HEADS, B_), block 384.  Kf is 32-wide (k only).
// ---------------------------------------------------------------------------
struct FS {
    union {
        float xs[128 * XP32];        // 33792 B fp32 x-chunk [c=128][n=64]
        float cbuf[3][64][CPITCH];   // 27648 B
    } u;
};

__global__ __launch_bounds__(384, 4)
void fproj_kernel(const float* __restrict__ x,
                  const float* __restrict__ wq, const float* __restrict__ wk,
                  const float* __restrict__ wv,
                  const float* __restrict__ bq, const float* __restrict__ bk,
                  const float* __restrict__ bv,
                  const float* __restrict__ rel_d, const float* __restrict__ rel_h,
                  const float* __restrict__ rel_w,
                  short* __restrict__ Qf, short* __restrict__ Kf,
                  short* __restrict__ Vf) {
    __shared__ FS sm;
    int nb = blockIdx.x * 64, h = blockIdx.y, b = blockIdx.z;
    int bh = b * HEADS + h;
    int t = threadIdx.x;
    int w = t >> 6, l = t & 63, ln = l & 31, hv = l >> 5;
    int mat = w >> 1, nh = w & 1;

    // ---- pos -> Qf upper half (global-only; overlaps staging, no LDS) ----
    if (t < 256) {
        int n_ = t >> 2, dd0 = (t & 3) * 8;
        int n = nb + n_;
        int di = n / 144, wi = (n / 12) % 12, hi = n % 12;
        H8 ph;
        #pragma unroll
        for (int o = 0; o < 8; o++) {
            int hd = h * DK + dd0 + o;
            ph.h[o] = (_Float16)(rel_d[hd * 12 + di] + rel_w[hd * 12 + wi] +
                                 rel_h[hd * 12 + hi]);
        }
        *(uint4*)&Qf[((size_t)bh * NVOX + n) * DE + DK + dd0] = ph.v;
    }

    const float* wsrc = (mat == 0) ? wq : (mat == 1) ? wk : wv;
    const float* wA = wsrc + (size_t)(h * DK + ln) * C_;   // this lane's W row
    const float* xb = x + (size_t)b * C_ * NVOX + nb;      // x[b][c][nb+..]
    int col = nh * 32 + ln;

    f32x16 acc;
    #pragma unroll
    for (int r = 0; r < 16; r++) acc[r] = 0.f;

    #pragma unroll 1
    for (int ch = 0; ch < 2; ch++) {
        __syncthreads();
        // stage fp32 chunk: [c 128][n 64], float2 per lane (coalesced 256B rows)
        for (int e = t; e < 4096; e += 384) {
            int ci = e >> 5, n2 = (e & 31) * 2;
            *(float2*)&sm.u.xs[ci * XP32 + n2] =
                *(const float2*)&xb[(size_t)(ch * 128 + ci) * NVOX + n2];
        }
        __syncthreads();
        #pragma unroll 4
        for (int ks = 0; ks < 8; ks++) {
            int kl_ = ks * 16 + hv * 8;
            // A: weight row fp32 -> f16x8
            float4 w0 = *(const float4*)&wA[ch * 128 + kl_];
            float4 w1 = *(const float4*)&wA[ch * 128 + kl_ + 4];
            H8 ah;
            ah.h[0] = (_Float16)w0.x; ah.h[1] = (_Float16)w0.y;
            ah.h[2] = (_Float16)w0.z; ah.h[3] = (_Float16)w0.w;
            ah.h[4] = (_Float16)w1.x; ah.h[5] = (_Float16)w1.y;
            ah.h[6] = (_Float16)w1.z; ah.h[7] = (_Float16)w1.w;
            // B: x^T frag: 8 c-rows at this lane's n-column (all-bank spread)
            H8 bh8;
            #pragma unroll
            for (int j = 0; j < 8; j++)
                bh8.h[j] = (_Float16)sm.u.xs[(kl_ + j) * XP32 + col];
            acc = mfma32h(*(const f16x8*)&ah, *(const f16x8*)&bh8, acc);
        }
    }
    __syncthreads();   // x tile dead; reuse as cbuf

    const float* bias = (mat == 0) ? bq : (mat == 1) ? bk : bv;
    #pragma unroll
    for (int q2 = 0; q2 < 4; q2++) {
        float4 cv;
        float* cvp = (float*)&cv;
        #pragma unroll
        for (int m = 0; m < 4; m++) {
            int o_loc = 8 * q2 + 4 * hv + m;
            cvp[m] = acc[4 * q2 + m] + bias[h * DK + o_loc];
        }
        *(float4*)&sm.u.cbuf[mat][col][8 * q2 + 4 * hv] = cv;
    }
    __syncthreads();

    if (t < 256) {                          // ---- readout q/k ----
        int n = t >> 2, ddg = (t & 3) * 8;
        H8 qh, kh;
        #pragma unroll
        for (int j = 0; j < 8; j++) {
            qh.h[j] = (_Float16)sm.u.cbuf[0][n][ddg + j];
            kh.h[j] = (_Float16)sm.u.cbuf[1][n][ddg + j];
        }
        *(uint4*)&Qf[((size_t)bh * NVOX + nb + n) * DE + ddg] = qh.v;
        *(uint4*)&Kf[((size_t)bh * NVOX + nb + n) * DK + ddg] = kh.v;
    }
    if (t < 256) {                          // ---- readout v ----
        int d = t >> 3, ng = (t & 7) * 8;
        H8 vv;
        #pragma unroll
        for (int j = 0; j < 8; j++)
            vv.h[j] = (_Float16)sm.u.cbuf[2][ng + j][d];
        *(uint4*)&Vf[((size_t)bh * DK + d) * NVOX + nb + ng] = vv.v;
    }
}

// ---------------------------------------------------------------------------
// Flash attention partial (UNCHANGED from R5 — proven):
//  - 4 waves/block, i-tile 128; fragment-major XOR-swizzled LDS (0 conflicts)
//  - global_load_lds staging, double-buffered, 1 barrier/iter
//  - P in-register via cvt_pkrtz + permlane32_swap; defer-max (THR=4, log2)
//  - T1 bijective XCD swizzle (FETCH 62.6 -> 6.95 MB); T5 setprio
//  launch_bounds(256,4): VGPR cap 128 — (256,6) spilled everything (R2).
// ---------------------------------------------------------------------------
__global__ __launch_bounds__(256, 4)
void attn_kernel(const short* __restrict__ Qf, const short* __restrict__ Kf,
                 const short* __restrict__ Vf,
                 short* __restrict__ wsO, float* __restrict__ wsM,
                 float* __restrict__ wsL) {
    __shared__ __align__(16) short Ksm[2][4096];
    __shared__ __align__(16) short Vsm[2][2048];
    // ---- XCD-clustering decode: id = x8 + 8*(k + 42*g), bh = 8g + x8 ----
    int id = blockIdx.x;
    int x8 = id & 7;
    int rr = id >> 3;            // 0..167
    int g  = rr / 42;            // 0..3
    int k_ = rr - g * 42;        // 0..41
    int bh = g * 8 + x8;
    int it = k_ / 3;
    int jp = k_ - it * 3;
    int t = threadIdx.x;
    int w  = t >> 6;       // wave 0..3
    int l  = t & 63;
    int ln = l & 31;
    int hv = l >> 5;
    int i_glob = it * 128 + w * 32 + ln;
    int iq = i_glob < NVOX ? i_glob : NVOX - 1;

    const short* Qp = Qf + (size_t)bh * NVOX * DE;
    const short* Kp = Kf + (size_t)bh * NVOX * DK;
    const short* Vp = Vf + (size_t)bh * DK * NVOX;

    f16x8 qf[4];
    #pragma unroll
    for (int ks = 0; ks < 4; ks++)
        qf[ks] = *(const f16x8*)&Qp[(size_t)iq * DE + ks * 16 + hv * 8];

    int jb0 = jp * NJT * 64;

    const short* gk0 = Kp + (size_t)(jb0 + (l ^ (w + 0))) * DK + (w + 0) * 8;
    const short* gk1 = Qp + (size_t)(jb0 + (l ^ (w + 4))) * DE + (w + 0) * 8;
    int vb0 = 2 * w + hv;
    const short* gv0 = Vp + (size_t)(ln ^ vb0) * NVOX + jb0 + vb0 * 8;

#define STAGE(bufp) do {                                   \
        short* kl_ = &Ksm[bufp][0];                        \
        short* vl_ = &Vsm[bufp][0];                        \
        gl_lds16(gk0, kl_ + (w + 0) * 512);                \
        gl_lds16(gk1, kl_ + (w + 4) * 512);                \
        gl_lds16(gv0, vl_ + (w + 0) * 512);                \
        gk0 += 64 * DK; gk1 += 64 * DE; gv0 += 64;         \
    } while (0)

    float mL = -INFINITY;
    float lsum = 0.f;
    f32x16 O;
    #pragma unroll
    for (int r = 0; r < 16; r++) O[r] = 0.f;

    STAGE(0);

    #pragma unroll 1
    for (int jt = 0; jt < NJT; ++jt) {
        int buf = jt & 1;
        __syncthreads();
        if (jt + 1 < NJT) STAGE(buf ^ 1);

        const short* Kb = &Ksm[buf][0];
        const short* Vb = &Vsm[buf][0];

        f32x16 sc[2];
        __builtin_amdgcn_s_setprio(1);
        #pragma unroll
        for (int js = 0; js < 2; js++) {
            f32x16 s;
            #pragma unroll
            for (int r = 0; r < 16; r++) s[r] = 0.f;
            #pragma unroll
            for (int ks = 0; ks < 4; ks++) {
                int kb = ks * 2 + hv;
                f16x8 kfr = *(const f16x8*)&Kb[kb * 512 + js * 256 + (ln ^ kb) * 8];
                s = mfma32h(kfr, qf[ks], s);
            }
            sc[js] = s;
        }
        __builtin_amdgcn_s_setprio(0);

        float m0 = fmaxf(sc[0][0], sc[1][0]);
        float m1 = fmaxf(sc[0][1], sc[1][1]);
        float m2 = fmaxf(sc[0][2], sc[1][2]);
        float m3 = fmaxf(sc[0][3], sc[1][3]);
        #pragma unroll
        for (int r = 4; r < 16; r += 4) {
            m0 = fmaxf(m0, fmaxf(sc[0][r + 0], sc[1][r + 0]));
            m1 = fmaxf(m1, fmaxf(sc[0][r + 1], sc[1][r + 1]));
            m2 = fmaxf(m2, fmaxf(sc[0][r + 2], sc[1][r + 2]));
            m3 = fmaxf(m3, fmaxf(sc[0][r + 3], sc[1][r + 3]));
        }
        float mx = fmaxf(fmaxf(m0, m1), fmaxf(m2, m3));
        mx = fmaxf(mx, __shfl_xor(mx, 32));
        float mxl = mx * LOG2E;
        if (!__all(mxl <= mL + 4.0f)) {
            float mLn = fmaxf(mL, mxl);
            float alpha = exp2f(mL - mLn);
            mL = mLn;
            lsum *= alpha;
            #pragma unroll
            for (int r = 0; r < 16; r++) O[r] *= alpha;
        }

        float ps0 = 0.f, ps1 = 0.f, ps2 = 0.f, ps3 = 0.f;
        #pragma unroll
        for (int js = 0; js < 2; js++) {
            #pragma unroll
            for (int r = 0; r < 16; r += 4) {
                float p0 = exp2f(fmaf(sc[js][r + 0], LOG2E, -mL));
                float p1 = exp2f(fmaf(sc[js][r + 1], LOG2E, -mL));
                float p2 = exp2f(fmaf(sc[js][r + 2], LOG2E, -mL));
                float p3 = exp2f(fmaf(sc[js][r + 3], LOG2E, -mL));
                sc[js][r + 0] = p0; sc[js][r + 1] = p1;
                sc[js][r + 2] = p2; sc[js][r + 3] = p3;
                ps0 += p0; ps1 += p1; ps2 += p2; ps3 += p3;
            }
        }
        float ps = (ps0 + ps1) + (ps2 + ps3);
        ps += __shfl_xor(ps, 32);
        lsum += ps;

        __builtin_amdgcn_s_setprio(1);
        #pragma unroll
        for (int ks = 0; ks < 4; ks++) {
            int js = ks >> 1, u8 = (ks & 1) * 8;
            PW a0p, a1p, b0p, b1p;
            a0p.h2 = __builtin_amdgcn_cvt_pkrtz(sc[js][u8 + 0], sc[js][u8 + 1]);
            a1p.h2 = __builtin_amdgcn_cvt_pkrtz(sc[js][u8 + 2], sc[js][u8 + 3]);
            b0p.h2 = __builtin_amdgcn_cvt_pkrtz(sc[js][u8 + 4], sc[js][u8 + 5]);
            b1p.h2 = __builtin_amdgcn_cvt_pkrtz(sc[js][u8 + 6], sc[js][u8 + 7]);
            auto r0 = __builtin_amdgcn_permlane32_swap(a0p.u, b0p.u, false, false);
            auto r1 = __builtin_amdgcn_permlane32_swap(a1p.u, b1p.u, false, false);
            union { unsigned int w4[4]; f16x8 f; } pb;
            pb.w4[0] = r0[0]; pb.w4[1] = r1[0];
            pb.w4[2] = r0[1]; pb.w4[3] = r1[1];
            int vb = ks * 2 + hv;
            f16x8 va = *(const f16x8*)&Vb[vb * 256 + (ln ^ vb) * 8];
            O = mfma32h(va, pb.f, O);
        }
        __builtin_amdgcn_s_setprio(0);
    }
#undef STAGE

    if (i_glob < NVOX) {
        short* Op = wsO + ((size_t)jp * (B_ * HEADS) + bh) * DK * NVOX;
        #pragma unroll
        for (int r = 0; r < 16; r++) {
            int d = (r & 3) + 8 * (r >> 2) + 4 * hv;
            _Float16 oh = (_Float16)O[r];
            Op[(size_t)d * NVOX + i_glob] = *(short*)&oh;
        }
        if (hv == 0) {
            size_t mo = ((size_t)jp * (B_ * HEADS) + bh) * NVOX + i_glob;
            wsM[mo] = mL;
            wsL[mo] = lsum;
        }
    }
}

// ---------------------------------------------------------------------------
// Combine the three j-third partials (flash merge identity), 4-wide vectorized.
// ---------------------------------------------------------------------------
__global__ void combine_kernel(const short* __restrict__ wsO,
                               const float* __restrict__ wsM,
                               const float* __restrict__ wsL,
                               float* __restrict__ out) {
    int idx = (blockIdx.x * 256 + threadIdx.x) * 4;   // 1,769,472 total
    int i = idx % NVOX;
    int bh = (idx / NVOX) >> 5;
    const size_t oh = (size_t)B_ * HEADS * DK * NVOX;
    const size_t mh = (size_t)B_ * HEADS * NVOX;
    size_t mo = (size_t)bh * NVOX + i;
    float4 m0 = *(const float4*)&wsM[mo];
    float4 m1 = *(const float4*)&wsM[mh + mo];
    float4 m2 = *(const float4*)&wsM[2 * mh + mo];
    float4 l0 = *(const float4*)&wsL[mo];
    float4 l1 = *(const float4*)&wsL[mh + mo];
    float4 l2 = *(const float4*)&wsL[2 * mh + mo];
    uint2 o0u = *(const uint2*)&wsO[idx];
    uint2 o1u = *(const uint2*)&wsO[oh + idx];
    uint2 o2u = *(const uint2*)&wsO[2 * oh + idx];
    const short* o0s = (const short*)&o0u;
    const short* o1s = (const short*)&o1u;
    const short* o2s = (const short*)&o2u;
    const float* m0p = (const float*)&m0; const float* m1p = (const float*)&m1;
    const float* m2p = (const float*)&m2;
    const float* l0p = (const float*)&l0; const float* l1p = (const float*)&l1;
    const float* l2p = (const float*)&l2;
    float4 res;
    float* rp = (float*)&res;
    #pragma unroll
    for (int j = 0; j < 4; j++) {
        float m = fmaxf(fmaxf(m0p[j], m1p[j]), m2p[j]);
        float a0 = exp2f(m0p[j] - m);
        float a1 = exp2f(m1p[j] - m);
        float a2 = exp2f(m2p[j] - m);
        rp[j] = (a0 * h2f(o0s[j]) + a1 * h2f(o1s[j]) + a2 * h2f(o2s[j])) /
                (a0 * l0p[j] + a1 * l1p[j] + a2 * l2p[j]);
    }
    *(float4*)&out[idx] = res;
}

// ---------------------------------------------------------------------------
extern "C" void kernel_launch(void* const* d_in, const int* in_sizes, int n_in,
                              void* d_out, int out_size, void* d_ws, size_t ws_size,
                              hipStream_t stream) {
    const float* x     = (const float*)d_in[0];
    const float* wq    = (const float*)d_in[1];
    const float* bq    = (const float*)d_in[2];
    const float* wk    = (const float*)d_in[3];
    const float* bk    = (const float*)d_in[4];
    const float* wv    = (const float*)d_in[5];
    const float* bv    = (const float*)d_in[6];
    const float* rel_d = (const float*)d_in[7];
    const float* rel_h = (const float*)d_in[8];
    const float* rel_w = (const float*)d_in[9];
    float* out = (float*)d_out;

    size_t qksz = (size_t)B_ * HEADS * NVOX * DE;        // 3,538,944
    size_t vsz  = (size_t)B_ * HEADS * DK * NVOX;        // 1,769,472
    short* Qf  = (short*)d_ws;
    short* Kf  = Qf + qksz;                              // 32-wide: vsz shorts
    short* Vf  = Kf + vsz;
    short* wsO = Vf + vsz;                               // 3*vsz shorts (f16)
    float* wsM = (float*)(wsO + 3 * vsz);                // 3*B*H*NVOX floats
    float* wsL = wsM + 3 * (size_t)B_ * HEADS * NVOX;

    fproj_kernel<<<dim3(NVOX / 64, HEADS, B_), dim3(384), 0, stream>>>(
        x, wq, wk, wv, bq, bk, bv, rel_d, rel_h, rel_w, Qf, Kf, Vf);
    attn_kernel<<<dim3(ITILES * JSPLIT * HEADS * B_), dim3(256), 0, stream>>>(
        Qf, Kf, Vf, wsO, wsM, wsL);
    combine_kernel<<<dim3((int)(vsz / 1024)), dim3(256), 0, stream>>>(wsO, wsM, wsL, out);
}

// Round 7
// 153.802 us; speedup vs baseline: 1.1130x; 1.1130x over previous
//
#include <hip/hip_runtime.h>
#include <math.h>

#define HEADS 8
#define DK 32
#define B_ 4
#define C_ 256
#define NVOX 1728   // 12*12*12
#define DE 64       // effective head dim: Q'=[q;pos], K'=[k;q]
#define XPITCH 136  // fproj x-chunk LDS pitch (shorts)
#define CPITCH 36   // fproj cbuf pitch (floats)
#define LOG2E 1.44269504088896f
#define JSPLIT 3    // j-dimension split (27 = 3*9 tiles)
#define NJT 9       // j-tiles per block (split 5+4 across two wave-groups)
#define ITILES 14   // ceil(1728/128) i-tiles (tail masked)

typedef _Float16 f16x8 __attribute__((ext_vector_type(8)));
typedef __fp16 fp16x2 __attribute__((ext_vector_type(2)));
typedef float f32x16 __attribute__((ext_vector_type(16)));

__device__ inline float h2f(short s) {
    _Float16 h = *(_Float16*)&s;
    return (float)h;
}
__device__ inline f32x16 mfma32h(f16x8 a, f16x8 b, f32x16 c) {
    return __builtin_amdgcn_mfma_f32_32x32x16_f16(a, b, c, 0, 0, 0);
}
// async global->LDS DMA, 16B per lane; LDS dest = wave-uniform base + lane*16
__device__ __forceinline__ void gl_lds16(const short* g, short* l) {
    __builtin_amdgcn_global_load_lds(
        (const __attribute__((address_space(1))) unsigned int*)g,
        (__attribute__((address_space(3))) unsigned int*)l, 16, 0, 0);
}

union H8 { _Float16 h[8]; uint4 v; };
union H4 { _Float16 h[4]; uint2 v; };
union PW { fp16x2 h2; unsigned int u; };

// ---------------------------------------------------------------------------
// Fused prep (R5-proven): [0,192) w->f16 | [192,624) x transpose | [624,1488) pos
// ---------------------------------------------------------------------------
__global__ __launch_bounds__(256)
void prep_kernel(const float* __restrict__ x,
                 const float* __restrict__ wq, const float* __restrict__ wk,
                 const float* __restrict__ wv,
                 const float* __restrict__ rel_d, const float* __restrict__ rel_h,
                 const float* __restrict__ rel_w,
                 short* __restrict__ wf, short* __restrict__ xf,
                 short* __restrict__ Qf) {
    __shared__ float tile[64][65];
    int bid = blockIdx.x;
    int t = threadIdx.x;

    if (bid < 192) {                       // ---- weights -> f16 (x4) ----
        int idx = (bid * 256 + t) * 4;     // 3*65536 total
        int m = idx >> 16;
        const float* w = (m == 0) ? wq : (m == 1) ? wk : wv;
        float4 v = *(const float4*)&w[idx & 65535];
        H4 hh;
        hh.h[0] = (_Float16)v.x; hh.h[1] = (_Float16)v.y;
        hh.h[2] = (_Float16)v.z; hh.h[3] = (_Float16)v.w;
        *(uint2*)&wf[idx] = hh.v;
    } else if (bid < 624) {                // ---- x[b][c][n] -> xf[b][n][c] ----
        int q = bid - 192;                 // 432 blocks: (27, 4, 4)
        int nb = (q % 27) * 64;
        int c0 = ((q / 27) % 4) * 64;
        int b  = q / 108;
        const float* xb = x + (size_t)b * C_ * NVOX;
        for (int e = t; e < 4096; e += 256) {
            int ci = e >> 6, nl = e & 63;
            tile[ci][nl] = xb[(size_t)(c0 + ci) * NVOX + nb + nl];
        }
        __syncthreads();
        for (int e = t; e < 512; e += 256) {
            int n = e >> 3, cg = (e & 7) * 8;
            H8 hi;
            #pragma unroll
            for (int j = 0; j < 8; j++) hi.h[j] = (_Float16)tile[cg + j][n];
            *(uint4*)&xf[((size_t)b * NVOX + nb + n) * C_ + c0 + cg] = hi.v;
        }
    } else {                               // ---- pos -> Q' upper half ----
        int q = bid - 624;                 // 864 blocks: (27, 8, 4)
        int nb = (q % 27) * 64;
        int h  = (q / 27) % 8;
        int b  = q / 216;
        int bh = b * HEADS + h;
        int nl = t & 63, dd0 = (t >> 6) * 8;
        int n = nb + nl;
        int di = n / 144, wi = (n / 12) % 12, hi = n % 12;
        H8 ph;
        #pragma unroll
        for (int o = 0; o < 8; o++) {
            int hd = h * DK + dd0 + o;
            ph.h[o] = (_Float16)(rel_d[hd * 12 + di] + rel_w[hd * 12 + wi] +
                                 rel_h[hd * 12 + hi]);
        }
        *(uint4*)&Qf[((size_t)bh * NVOX + n) * DE + DK + dd0] = ph.v;
    }
}

// ---------------------------------------------------------------------------
// MFMA projection (R5-proven). grid (27, HEADS, B_), block 384.
// ---------------------------------------------------------------------------
struct FS {
    union {
        short xs[64 * XPITCH];
        float cbuf[3][64][CPITCH];
    } u;
};

__global__ __launch_bounds__(384, 4)
void fproj_kernel(const short* __restrict__ xf, const short* __restrict__ wf,
                  const float* __restrict__ bq, const float* __restrict__ bk,
                  const float* __restrict__ bv,
                  short* __restrict__ Qf, short* __restrict__ Kf,
                  short* __restrict__ Vf) {
    __shared__ FS sm;
    int nb = blockIdx.x * 64, h = blockIdx.y, b = blockIdx.z;
    int bh = b * HEADS + h;
    int t = threadIdx.x;
    int w = t >> 6, l = t & 63, ln = l & 31, hv = l >> 5;
    int mat = w >> 1, nh = w & 1;

    const short* xb = xf + ((size_t)b * NVOX + nb) * C_;
    const short* wA = wf + ((size_t)mat * C_ + h * DK + ln) * C_;
    int xrow = (nh * 32 + ln) * XPITCH;

    f32x16 acc;
    #pragma unroll
    for (int r = 0; r < 16; r++) acc[r] = 0.f;

    #pragma unroll 1
    for (int ch = 0; ch < 2; ch++) {
        __syncthreads();
        for (int e = t; e < 1024; e += 384) {
            int row = e >> 4, c8 = (e & 15) * 8;
            *(uint4*)&sm.u.xs[row * XPITCH + c8] =
                *(const uint4*)&xb[row * C_ + ch * 128 + c8];
        }
        __syncthreads();
        #pragma unroll 4
        for (int ks = 0; ks < 8; ks++) {
            int kl_ = ks * 16 + hv * 8;
            f16x8 a = *(const f16x8*)&wA[ch * 128 + kl_];
            f16x8 bfr = *(const f16x8*)&sm.u.xs[xrow + kl_];
            acc = mfma32h(a, bfr, acc);
        }
    }
    __syncthreads();   // x tile dead; reuse as cbuf

    const float* bias = (mat == 0) ? bq : (mat == 1) ? bk : bv;
    int ncol = nh * 32 + ln;
    #pragma unroll
    for (int q2 = 0; q2 < 4; q2++) {
        float4 cv;
        float* cvp = (float*)&cv;
        #pragma unroll
        for (int m = 0; m < 4; m++) {
            int o_loc = 8 * q2 + 4 * hv + m;
            cvp[m] = acc[4 * q2 + m] + bias[h * DK + o_loc];
        }
        *(float4*)&sm.u.cbuf[mat][ncol][8 * q2 + 4 * hv] = cv;
    }
    __syncthreads();

    if (t < 256) {                          // ---- readout q/k ----
        int n = t >> 2, ddg = (t & 3) * 8;
        H8 qh, kh;
        #pragma unroll
        for (int j = 0; j < 8; j++) {
            qh.h[j] = (_Float16)sm.u.cbuf[0][n][ddg + j];
            kh.h[j] = (_Float16)sm.u.cbuf[1][n][ddg + j];
        }
        *(uint4*)&Qf[((size_t)bh * NVOX + nb + n) * DE + ddg] = qh.v;
        *(uint4*)&Kf[((size_t)bh * NVOX + nb + n) * DK + ddg] = kh.v;
    }
    if (t < 256) {                          // ---- readout v ----
        int d = t >> 3, ng = (t & 7) * 8;
        H8 vv;
        #pragma unroll
        for (int j = 0; j < 8; j++)
            vv.h[j] = (_Float16)sm.u.cbuf[2][ng + j][d];
        *(uint4*)&Vf[((size_t)bh * DK + d) * NVOX + nb + ng] = vv.v;
    }
}

// ---------------------------------------------------------------------------
// Flash attention partial, 8 waves / 2 j-groups:
//  - group0 (waves 0-3): j-tiles 0-4; group1 (waves 4-7): j-tiles 5-8
//    (group1's 5th loop iteration is barrier-only, keeping counts uniform)
//  - each group: own double-buffered XOR-swizzled K/V LDS (24.5 KB x2),
//    global_load_lds staging, P in-register (cvt_pkrtz+permlane32_swap),
//    defer-max; T1 XCD swizzle; T5 setprio — all R5-proven
//  - in-block flash merge (f32, via dead LDS) -> same 3 global partials
//  grid 1344 blocks, block 512.  Halves the per-block j-serial chain.
// ---------------------------------------------------------------------------
struct AS { short K[2][4096]; short V[2][2048]; };   // 24576 B per group

__global__ __launch_bounds__(512, 4)
void attn_kernel(const short* __restrict__ Qf, const short* __restrict__ Kf,
                 const short* __restrict__ Vf,
                 short* __restrict__ wsO, float* __restrict__ wsM,
                 float* __restrict__ wsL) {
    __shared__ __align__(16) AS gsm[2];              // 49152 B total
    // ---- XCD-clustering decode: id = x8 + 8*(k + 42*g), bh = 8g + x8 ----
    int id = blockIdx.x;
    int x8 = id & 7;
    int rr = id >> 3;            // 0..167
    int g  = rr / 42;            // 0..3
    int k_ = rr - g * 42;        // 0..41
    int bh = g * 8 + x8;
    int it = k_ / 3;
    int jp = k_ - it * 3;
    int t = threadIdx.x;
    int w  = t >> 6;       // wave 0..7
    int grp = w >> 2;      // j-group 0/1
    int wl  = w & 3;       // role within group
    int l  = t & 63;
    int ln = l & 31;
    int hv = l >> 5;
    int i_glob = it * 128 + wl * 32 + ln;
    int iq = i_glob < NVOX ? i_glob : NVOX - 1;

    int cnt   = grp ? 4 : 5;           // j-tiles this group owns
    int tile0 = grp ? 5 : 0;

    const short* Qp = Qf + (size_t)bh * NVOX * DE;
    const short* Kp = Kf + (size_t)bh * NVOX * DK;
    const short* Vp = Vf + (size_t)bh * DK * NVOX;

    f16x8 qf[4];
    #pragma unroll
    for (int ks = 0; ks < 4; ks++)
        qf[ks] = *(const f16x8*)&Qp[(size_t)iq * DE + ks * 16 + hv * 8];

    int jb0 = jp * NJT * 64 + tile0 * 64;

    // staging: within a group, wave wl owns K'-chunks {wl, wl+4}, V-region wl
    const short* gk0 = Kp + (size_t)(jb0 + (l ^ (wl + 0))) * DK + (wl + 0) * 8;
    const short* gk1 = Qp + (size_t)(jb0 + (l ^ (wl + 4))) * DE + (wl + 0) * 8;
    int vb0 = 2 * wl + hv;
    const short* gv0 = Vp + (size_t)(ln ^ vb0) * NVOX + jb0 + vb0 * 8;

#define STAGE(bufp) do {                                   \
        short* kl_ = &gsm[grp].K[bufp][0];                 \
        short* vl_ = &gsm[grp].V[bufp][0];                 \
        gl_lds16(gk0, kl_ + (wl + 0) * 512);               \
        gl_lds16(gk1, kl_ + (wl + 4) * 512);               \
        gl_lds16(gv0, vl_ + (wl + 0) * 512);               \
        gk0 += 64 * DK; gk1 += 64 * DE; gv0 += 64;         \
    } while (0)

    float mL = -INFINITY;
    float lsum = 0.f;
    f32x16 O;
    #pragma unroll
    for (int r = 0; r < 16; r++) O[r] = 0.f;

    STAGE(0);   // prologue prefetch (both groups)

    #pragma unroll 1
    for (int s = 0; s < 5; ++s) {
        int buf = s & 1;
        __syncthreads();                 // uniform: 5 barriers for all waves
        if (s + 1 < cnt) STAGE(buf ^ 1);
        if (s < cnt) {
            const short* Kb = &gsm[grp].K[buf][0];
            const short* Vb = &gsm[grp].V[buf][0];

            // ---- S^T: two 32x32 j-subtiles, conflict-free reads ----
            f32x16 sc[2];
            __builtin_amdgcn_s_setprio(1);
            #pragma unroll
            for (int js = 0; js < 2; js++) {
                f32x16 s_;
                #pragma unroll
                for (int r = 0; r < 16; r++) s_[r] = 0.f;
                #pragma unroll
                for (int ks = 0; ks < 4; ks++) {
                    int kb = ks * 2 + hv;
                    f16x8 kfr = *(const f16x8*)&Kb[kb * 512 + js * 256 + (ln ^ kb) * 8];
                    s_ = mfma32h(kfr, qf[ks], s_);
                }
                sc[js] = s_;
            }
            __builtin_amdgcn_s_setprio(0);

            // ---- online softmax with defer-max ----
            float m0 = fmaxf(sc[0][0], sc[1][0]);
            float m1 = fmaxf(sc[0][1], sc[1][1]);
            float m2 = fmaxf(sc[0][2], sc[1][2]);
            float m3 = fmaxf(sc[0][3], sc[1][3]);
            #pragma unroll
            for (int r = 4; r < 16; r += 4) {
                m0 = fmaxf(m0, fmaxf(sc[0][r + 0], sc[1][r + 0]));
                m1 = fmaxf(m1, fmaxf(sc[0][r + 1], sc[1][r + 1]));
                m2 = fmaxf(m2, fmaxf(sc[0][r + 2], sc[1][r + 2]));
                m3 = fmaxf(m3, fmaxf(sc[0][r + 3], sc[1][r + 3]));
            }
            float mx = fmaxf(fmaxf(m0, m1), fmaxf(m2, m3));
            mx = fmaxf(mx, __shfl_xor(mx, 32));
            float mxl = mx * LOG2E;
            if (!__all(mxl <= mL + 4.0f)) {
                float mLn = fmaxf(mL, mxl);
                float alpha = exp2f(mL - mLn);
                mL = mLn;
                lsum *= alpha;
                #pragma unroll
                for (int r = 0; r < 16; r++) O[r] *= alpha;
            }

            float ps0 = 0.f, ps1 = 0.f, ps2 = 0.f, ps3 = 0.f;
            #pragma unroll
            for (int js = 0; js < 2; js++) {
                #pragma unroll
                for (int r = 0; r < 16; r += 4) {
                    float p0 = exp2f(fmaf(sc[js][r + 0], LOG2E, -mL));
                    float p1 = exp2f(fmaf(sc[js][r + 1], LOG2E, -mL));
                    float p2 = exp2f(fmaf(sc[js][r + 2], LOG2E, -mL));
                    float p3 = exp2f(fmaf(sc[js][r + 3], LOG2E, -mL));
                    sc[js][r + 0] = p0; sc[js][r + 1] = p1;
                    sc[js][r + 2] = p2; sc[js][r + 3] = p3;
                    ps0 += p0; ps1 += p1; ps2 += p2; ps3 += p3;
                }
            }
            float ps = (ps0 + ps1) + (ps2 + ps3);
            ps += __shfl_xor(ps, 32);
            lsum += ps;

            // ---- O^T += Vt * P : P fragment built in-register ----
            __builtin_amdgcn_s_setprio(1);
            #pragma unroll
            for (int ks = 0; ks < 4; ks++) {
                int js = ks >> 1, u8 = (ks & 1) * 8;
                PW a0p, a1p, b0p, b1p;
                a0p.h2 = __builtin_amdgcn_cvt_pkrtz(sc[js][u8 + 0], sc[js][u8 + 1]);
                a1p.h2 = __builtin_amdgcn_cvt_pkrtz(sc[js][u8 + 2], sc[js][u8 + 3]);
                b0p.h2 = __builtin_amdgcn_cvt_pkrtz(sc[js][u8 + 4], sc[js][u8 + 5]);
                b1p.h2 = __builtin_amdgcn_cvt_pkrtz(sc[js][u8 + 6], sc[js][u8 + 7]);
                auto r0 = __builtin_amdgcn_permlane32_swap(a0p.u, b0p.u, false, false);
                auto r1 = __builtin_amdgcn_permlane32_swap(a1p.u, b1p.u, false, false);
                union { unsigned int w4[4]; f16x8 f; } pb;
                pb.w4[0] = r0[0]; pb.w4[1] = r1[0];
                pb.w4[2] = r0[1]; pb.w4[3] = r1[1];
                int vb = ks * 2 + hv;
                f16x8 va = *(const f16x8*)&Vb[vb * 256 + (ln ^ vb) * 8];
                O = mfma32h(va, pb.f, O);
            }
            __builtin_amdgcn_s_setprio(0);
        }
    }
#undef STAGE

    // ---- in-block flash merge (f32 via dead LDS), then partial epilogue ----
    __syncthreads();                     // all compute done; K/V LDS dead
    float* mb = (float*)&gsm[0];
    int sl = wl * 64 + l;                // 0..255 within group
    if (grp == 1) {
        #pragma unroll
        for (int r = 0; r < 16; r++) mb[sl * 17 + r] = O[r];   // pitch 17: no 16-way conflict
        mb[4400 + sl] = mL;
        mb[4700 + sl] = lsum;
    }
    __syncthreads();
    if (grp == 0 && i_glob < NVOX) {
        float m1 = mb[4400 + sl];
        float l1 = mb[4700 + sl];
        float mm = fmaxf(mL, m1);
        float a0 = exp2f(mL - mm);
        float a1 = exp2f(m1 - mm);
        float lq = lsum * a0 + l1 * a1;
        short* Op = wsO + ((size_t)jp * (B_ * HEADS) + bh) * DK * NVOX;
        #pragma unroll
        for (int r = 0; r < 16; r++) {
            int d = (r & 3) + 8 * (r >> 2) + 4 * hv;
            _Float16 oh = (_Float16)(O[r] * a0 + mb[sl * 17 + r] * a1);
            Op[(size_t)d * NVOX + i_glob] = *(short*)&oh;
        }
        if (hv == 0) {
            size_t mo = ((size_t)jp * (B_ * HEADS) + bh) * NVOX + i_glob;
            wsM[mo] = mm;
            wsL[mo] = lq;
        }
    }
}

// ---------------------------------------------------------------------------
// Combine the three j-third partials (flash merge identity), 4-wide vectorized.
// ---------------------------------------------------------------------------
__global__ void combine_kernel(const short* __restrict__ wsO,
                               const float* __restrict__ wsM,
                               const float* __restrict__ wsL,
                               float* __restrict__ out) {
    int idx = (blockIdx.x * 256 + threadIdx.x) * 4;   // 1,769,472 total
    int i = idx % NVOX;
    int bh = (idx / NVOX) >> 5;
    const size_t oh = (size_t)B_ * HEADS * DK * NVOX;
    const size_t mh = (size_t)B_ * HEADS * NVOX;
    size_t mo = (size_t)bh * NVOX + i;
    float4 m0 = *(const float4*)&wsM[mo];
    float4 m1 = *(const float4*)&wsM[mh + mo];
    float4 m2 = *(const float4*)&wsM[2 * mh + mo];
    float4 l0 = *(const float4*)&wsL[mo];
    float4 l1 = *(const float4*)&wsL[mh + mo];
    float4 l2 = *(const float4*)&wsL[2 * mh + mo];
    uint2 o0u = *(const uint2*)&wsO[idx];
    uint2 o1u = *(const uint2*)&wsO[oh + idx];
    uint2 o2u = *(const uint2*)&wsO[2 * oh + idx];
    const short* o0s = (const short*)&o0u;
    const short* o1s = (const short*)&o1u;
    const short* o2s = (const short*)&o2u;
    const float* m0p = (const float*)&m0; const float* m1p = (const float*)&m1;
    const float* m2p = (const float*)&m2;
    const float* l0p = (const float*)&l0; const float* l1p = (const float*)&l1;
    const float* l2p = (const float*)&l2;
    float4 res;
    float* rp = (float*)&res;
    #pragma unroll
    for (int j = 0; j < 4; j++) {
        float m = fmaxf(fmaxf(m0p[j], m1p[j]), m2p[j]);
        float a0 = exp2f(m0p[j] - m);
        float a1 = exp2f(m1p[j] - m);
        float a2 = exp2f(m2p[j] - m);
        rp[j] = (a0 * h2f(o0s[j]) + a1 * h2f(o1s[j]) + a2 * h2f(o2s[j])) /
                (a0 * l0p[j] + a1 * l1p[j] + a2 * l2p[j]);
    }
    *(float4*)&out[idx] = res;
}

// ---------------------------------------------------------------------------
extern "C" void kernel_launch(void* const* d_in, const int* in_sizes, int n_in,
                              void* d_out, int out_size, void* d_ws, size_t ws_size,
                              hipStream_t stream) {
    const float* x     = (const float*)d_in[0];
    const float* wq    = (const float*)d_in[1];
    const float* bq    = (const float*)d_in[2];
    const float* wk    = (const float*)d_in[3];
    const float* bk    = (const float*)d_in[4];
    const float* wv    = (const float*)d_in[5];
    const float* bv    = (const float*)d_in[6];
    const float* rel_d = (const float*)d_in[7];
    const float* rel_h = (const float*)d_in[8];
    const float* rel_w = (const float*)d_in[9];
    float* out = (float*)d_out;

    size_t qksz = (size_t)B_ * HEADS * NVOX * DE;        // 3,538,944
    size_t vsz  = (size_t)B_ * HEADS * DK * NVOX;        // 1,769,472
    short* Qf  = (short*)d_ws;
    short* Kf  = Qf + qksz;                              // 32-wide: vsz shorts
    short* Vf  = Kf + vsz;
    short* wf  = Vf + vsz;                               // 196,608 shorts
    short* wsO = wf + (size_t)3 * C_ * C_;               // 3*vsz shorts (f16)
    float* wsM = (float*)(wsO + 3 * vsz);                // 3*B*H*NVOX floats
    float* wsL = wsM + 3 * (size_t)B_ * HEADS * NVOX;
    short* xf  = wsO;                                    // aliases wsO (dead before attn)

    prep_kernel<<<dim3(1488), dim3(256), 0, stream>>>(
        x, wq, wk, wv, rel_d, rel_h, rel_w, wf, xf, Qf);
    fproj_kernel<<<dim3(NVOX / 64, HEADS, B_), dim3(384), 0, stream>>>(
        xf, wf, bq, bk, bv, Qf, Kf, Vf);
    attn_kernel<<<dim3(ITILES * JSPLIT * HEADS * B_), dim3(512), 0, stream>>>(
        Qf, Kf, Vf, wsO, wsM, wsL);
    combine_kernel<<<dim3((int)(vsz / 1024)), dim3(256), 0, stream>>>(wsO, wsM, wsL, out);
}

// Round 8
// 152.171 us; speedup vs baseline: 1.1250x; 1.0107x over previous
//
#include <hip/hip_runtime.h>
#include <math.h>

#define HEADS 8
#define DK 32
#define B_ 4
#define C_ 256
#define NVOX 1728   // 12*12*12
#define DE 64       // effective head dim: Q'=[q;pos], K'=[k;q]
#define XPITCH 136  // fproj x-chunk LDS pitch (shorts)
#define CPITCH 36   // fproj cbuf pitch (floats)
#define LOG2E 1.44269504088896f
#define JSPLIT 3    // j-dimension split (27 = 3*9 tiles)
#define NJT 9       // j-tiles per block
#define ITILES 14   // ceil(1728/128) i-tiles (tail masked)

typedef _Float16 f16x8 __attribute__((ext_vector_type(8)));
typedef __fp16 fp16x2 __attribute__((ext_vector_type(2)));
typedef float f32x16 __attribute__((ext_vector_type(16)));

__device__ inline float h2f(short s) {
    _Float16 h = *(_Float16*)&s;
    return (float)h;
}
__device__ inline f32x16 mfma32h(f16x8 a, f16x8 b, f32x16 c) {
    return __builtin_amdgcn_mfma_f32_32x32x16_f16(a, b, c, 0, 0, 0);
}
// async global->LDS DMA, 16B per lane; LDS dest = wave-uniform base + lane*16
__device__ __forceinline__ void gl_lds16(const short* g, short* l) {
    __builtin_amdgcn_global_load_lds(
        (const __attribute__((address_space(1))) unsigned int*)g,
        (__attribute__((address_space(3))) unsigned int*)l, 16, 0, 0);
}

union H8 { _Float16 h[8]; uint4 v; };
union H4 { _Float16 h[4]; uint2 v; };
union PW { fp16x2 h2; unsigned int u; };

// ---------------------------------------------------------------------------
// Fused prep (R5-proven): [0,192) w->f16 | [192,624) x transpose | [624,1488) pos
// ---------------------------------------------------------------------------
__global__ __launch_bounds__(256)
void prep_kernel(const float* __restrict__ x,
                 const float* __restrict__ wq, const float* __restrict__ wk,
                 const float* __restrict__ wv,
                 const float* __restrict__ rel_d, const float* __restrict__ rel_h,
                 const float* __restrict__ rel_w,
                 short* __restrict__ wf, short* __restrict__ xf,
                 short* __restrict__ Qf) {
    __shared__ float tile[64][65];
    int bid = blockIdx.x;
    int t = threadIdx.x;

    if (bid < 192) {                       // ---- weights -> f16 (x4) ----
        int idx = (bid * 256 + t) * 4;     // 3*65536 total
        int m = idx >> 16;
        const float* w = (m == 0) ? wq : (m == 1) ? wk : wv;
        float4 v = *(const float4*)&w[idx & 65535];
        H4 hh;
        hh.h[0] = (_Float16)v.x; hh.h[1] = (_Float16)v.y;
        hh.h[2] = (_Float16)v.z; hh.h[3] = (_Float16)v.w;
        *(uint2*)&wf[idx] = hh.v;
    } else if (bid < 624) {                // ---- x[b][c][n] -> xf[b][n][c] ----
        int q = bid - 192;                 // 432 blocks: (27, 4, 4)
        int nb = (q % 27) * 64;
        int c0 = ((q / 27) % 4) * 64;
        int b  = q / 108;
        const float* xb = x + (size_t)b * C_ * NVOX;
        for (int e = t; e < 4096; e += 256) {
            int ci = e >> 6, nl = e & 63;
            tile[ci][nl] = xb[(size_t)(c0 + ci) * NVOX + nb + nl];
        }
        __syncthreads();
        for (int e = t; e < 512; e += 256) {
            int n = e >> 3, cg = (e & 7) * 8;
            H8 hi;
            #pragma unroll
            for (int j = 0; j < 8; j++) hi.h[j] = (_Float16)tile[cg + j][n];
            *(uint4*)&xf[((size_t)b * NVOX + nb + n) * C_ + c0 + cg] = hi.v;
        }
    } else {                               // ---- pos -> Q' upper half ----
        int q = bid - 624;                 // 864 blocks: (27, 8, 4)
        int nb = (q % 27) * 64;
        int h  = (q / 27) % 8;
        int b  = q / 216;
        int bh = b * HEADS + h;
        int nl = t & 63, dd0 = (t >> 6) * 8;
        int n = nb + nl;
        int di = n / 144, wi = (n / 12) % 12, hi = n % 12;
        H8 ph;
        #pragma unroll
        for (int o = 0; o < 8; o++) {
            int hd = h * DK + dd0 + o;
            ph.h[o] = (_Float16)(rel_d[hd * 12 + di] + rel_w[hd * 12 + wi] +
                                 rel_h[hd * 12 + hi]);
        }
        *(uint4*)&Qf[((size_t)bh * NVOX + n) * DE + DK + dd0] = ph.v;
    }
}

// ---------------------------------------------------------------------------
// MFMA projection (R5-proven). grid (27, HEADS, B_), block 384.
// ---------------------------------------------------------------------------
struct FS {
    union {
        short xs[64 * XPITCH];
        float cbuf[3][64][CPITCH];
    } u;
};

__global__ __launch_bounds__(384, 4)
void fproj_kernel(const short* __restrict__ xf, const short* __restrict__ wf,
                  const float* __restrict__ bq, const float* __restrict__ bk,
                  const float* __restrict__ bv,
                  short* __restrict__ Qf, short* __restrict__ Kf,
                  short* __restrict__ Vf) {
    __shared__ FS sm;
    int nb = blockIdx.x * 64, h = blockIdx.y, b = blockIdx.z;
    int bh = b * HEADS + h;
    int t = threadIdx.x;
    int w = t >> 6, l = t & 63, ln = l & 31, hv = l >> 5;
    int mat = w >> 1, nh = w & 1;

    const short* xb = xf + ((size_t)b * NVOX + nb) * C_;
    const short* wA = wf + ((size_t)mat * C_ + h * DK + ln) * C_;
    int xrow = (nh * 32 + ln) * XPITCH;

    f32x16 acc;
    #pragma unroll
    for (int r = 0; r < 16; r++) acc[r] = 0.f;

    #pragma unroll 1
    for (int ch = 0; ch < 2; ch++) {
        __syncthreads();
        for (int e = t; e < 1024; e += 384) {
            int row = e >> 4, c8 = (e & 15) * 8;
            *(uint4*)&sm.u.xs[row * XPITCH + c8] =
                *(const uint4*)&xb[row * C_ + ch * 128 + c8];
        }
        __syncthreads();
        #pragma unroll 4
        for (int ks = 0; ks < 8; ks++) {
            int kl_ = ks * 16 + hv * 8;
            f16x8 a = *(const f16x8*)&wA[ch * 128 + kl_];
            f16x8 bfr = *(const f16x8*)&sm.u.xs[xrow + kl_];
            acc = mfma32h(a, bfr, acc);
        }
    }
    __syncthreads();   // x tile dead; reuse as cbuf

    const float* bias = (mat == 0) ? bq : (mat == 1) ? bk : bv;
    int ncol = nh * 32 + ln;
    #pragma unroll
    for (int q2 = 0; q2 < 4; q2++) {
        float4 cv;
        float* cvp = (float*)&cv;
        #pragma unroll
        for (int m = 0; m < 4; m++) {
            int o_loc = 8 * q2 + 4 * hv + m;
            cvp[m] = acc[4 * q2 + m] + bias[h * DK + o_loc];
        }
        *(float4*)&sm.u.cbuf[mat][ncol][8 * q2 + 4 * hv] = cv;
    }
    __syncthreads();

    if (t < 256) {                          // ---- readout q/k ----
        int n = t >> 2, ddg = (t & 3) * 8;
        H8 qh, kh;
        #pragma unroll
        for (int j = 0; j < 8; j++) {
            qh.h[j] = (_Float16)sm.u.cbuf[0][n][ddg + j];
            kh.h[j] = (_Float16)sm.u.cbuf[1][n][ddg + j];
        }
        *(uint4*)&Qf[((size_t)bh * NVOX + nb + n) * DE + ddg] = qh.v;
        *(uint4*)&Kf[((size_t)bh * NVOX + nb + n) * DK + ddg] = kh.v;
    }
    if (t < 256) {                          // ---- readout v ----
        int d = t >> 3, ng = (t & 7) * 8;
        H8 vv;
        #pragma unroll
        for (int j = 0; j < 8; j++)
            vv.h[j] = (_Float16)sm.u.cbuf[2][ng + j][d];
        *(uint4*)&Vf[((size_t)bh * DK + d) * NVOX + nb + ng] = vv.v;
    }
}

// ---------------------------------------------------------------------------
// Flash attention partial (R5 structure + T3/T4 counted-vmcnt pipeline):
//  - 4 waves/block, i-tile 128; fragment-major XOR-swizzled LDS (0 conflicts)
//  - TRIPLE-buffered K/V, prefetch distance 2, raw s_barrier + counted
//    s_waitcnt vmcnt(3): tile jt+1's 3 DMA loads stay in flight ACROSS the
//    barrier (never drain to 0 in steady state) — removes the per-iter
//    vmcnt(0)+lgkmcnt(0) drain that __syncthreads imposes (m233's ~72%
//    2-phase overhead class).  Count accounting: 3 gl_lds per wave per
//    STAGE; at iter jt wait retires tile jt's 3 (issued 2 phases ago).
//    WAR safe: buf (jt+2)%3 last read at iter jt-1, two barriers back.
//  - P in-register (cvt_pkrtz+permlane32_swap); defer-max; T1 XCD swizzle;
//    T5 setprio.  launch_bounds(256,4): VGPR cap 128 (R2: (256,6) spilled).
//  grid 1344 blocks (= 8 XCD x 168), block 256.
// ---------------------------------------------------------------------------
__global__ __launch_bounds__(256, 4)
void attn_kernel(const short* __restrict__ Qf, const short* __restrict__ Kf,
                 const short* __restrict__ Vf,
                 short* __restrict__ wsO, float* __restrict__ wsM,
                 float* __restrict__ wsL) {
    __shared__ __align__(16) short Ksm[3][4096];
    __shared__ __align__(16) short Vsm[3][2048];
    // ---- XCD-clustering decode: id = x8 + 8*(k + 42*g), bh = 8g + x8 ----
    int id = blockIdx.x;
    int x8 = id & 7;
    int rr = id >> 3;            // 0..167
    int g  = rr / 42;            // 0..3
    int k_ = rr - g * 42;        // 0..41
    int bh = g * 8 + x8;
    int it = k_ / 3;
    int jp = k_ - it * 3;
    int t = threadIdx.x;
    int w  = t >> 6;       // wave 0..3
    int l  = t & 63;
    int ln = l & 31;
    int hv = l >> 5;
    int i_glob = it * 128 + w * 32 + ln;
    int iq = i_glob < NVOX ? i_glob : NVOX - 1;

    const short* Qp = Qf + (size_t)bh * NVOX * DE;
    const short* Kp = Kf + (size_t)bh * NVOX * DK;
    const short* Vp = Vf + (size_t)bh * DK * NVOX;

    f16x8 qf[4];
    #pragma unroll
    for (int ks = 0; ks < 4; ks++)
        qf[ks] = *(const f16x8*)&Qp[(size_t)iq * DE + ks * 16 + hv * 8];

    int jb0 = jp * NJT * 64;

    // staging: wave w owns K'-chunks {w, w+4} and V-region w (vb = 2w+hv)
    const short* gk0 = Kp + (size_t)(jb0 + (l ^ (w + 0))) * DK + (w + 0) * 8;
    const short* gk1 = Qp + (size_t)(jb0 + (l ^ (w + 4))) * DE + (w + 0) * 8;
    int vb0 = 2 * w + hv;
    const short* gv0 = Vp + (size_t)(ln ^ vb0) * NVOX + jb0 + vb0 * 8;

#define STAGE(bufp) do {                                   \
        short* kl_ = &Ksm[bufp][0];                        \
        short* vl_ = &Vsm[bufp][0];                        \
        gl_lds16(gk0, kl_ + (w + 0) * 512);                \
        gl_lds16(gk1, kl_ + (w + 4) * 512);                \
        gl_lds16(gv0, vl_ + (w + 0) * 512);                \
        gk0 += 64 * DK; gk1 += 64 * DE; gv0 += 64;         \
    } while (0)

    float mL = -INFINITY;
    float lsum = 0.f;
    f32x16 O;
    #pragma unroll
    for (int r = 0; r < 16; r++) O[r] = 0.f;

    STAGE(0);   // prefetch tile 0
    STAGE(1);   // prefetch tile 1 (depth 2)

    #pragma unroll 1
    for (int jt = 0; jt < NJT; ++jt) {
        // counted wait: retire tile jt's 3 loads; leave tile jt+1's in flight
        if (jt < NJT - 1) asm volatile("s_waitcnt vmcnt(3)" ::: "memory");
        else              asm volatile("s_waitcnt vmcnt(0)" ::: "memory");
        __builtin_amdgcn_sched_barrier(0);
        __builtin_amdgcn_s_barrier();
        __builtin_amdgcn_sched_barrier(0);
        if (jt + 2 < NJT) STAGE((jt + 2) % 3);

        const short* Kb = &Ksm[jt % 3][0];
        const short* Vb = &Vsm[jt % 3][0];

        // ---- S^T: two 32x32 j-subtiles, conflict-free operand reads ----
        f32x16 sc[2];
        __builtin_amdgcn_s_setprio(1);
        #pragma unroll
        for (int js = 0; js < 2; js++) {
            f32x16 s;
            #pragma unroll
            for (int r = 0; r < 16; r++) s[r] = 0.f;
            #pragma unroll
            for (int ks = 0; ks < 4; ks++) {
                int kb = ks * 2 + hv;
                f16x8 kfr = *(const f16x8*)&Kb[kb * 512 + js * 256 + (ln ^ kb) * 8];
                s = mfma32h(kfr, qf[ks], s);
            }
            sc[js] = s;
        }
        __builtin_amdgcn_s_setprio(0);

        // ---- online softmax with defer-max ----
        float m0 = fmaxf(sc[0][0], sc[1][0]);
        float m1 = fmaxf(sc[0][1], sc[1][1]);
        float m2 = fmaxf(sc[0][2], sc[1][2]);
        float m3 = fmaxf(sc[0][3], sc[1][3]);
        #pragma unroll
        for (int r = 4; r < 16; r += 4) {
            m0 = fmaxf(m0, fmaxf(sc[0][r + 0], sc[1][r + 0]));
            m1 = fmaxf(m1, fmaxf(sc[0][r + 1], sc[1][r + 1]));
            m2 = fmaxf(m2, fmaxf(sc[0][r + 2], sc[1][r + 2]));
            m3 = fmaxf(m3, fmaxf(sc[0][r + 3], sc[1][r + 3]));
        }
        float mx = fmaxf(fmaxf(m0, m1), fmaxf(m2, m3));
        mx = fmaxf(mx, __shfl_xor(mx, 32));
        float mxl = mx * LOG2E;
        if (!__all(mxl <= mL + 4.0f)) {
            float mLn = fmaxf(mL, mxl);
            float alpha = exp2f(mL - mLn);
            mL = mLn;
            lsum *= alpha;
            #pragma unroll
            for (int r = 0; r < 16; r++) O[r] *= alpha;
        }

        float ps0 = 0.f, ps1 = 0.f, ps2 = 0.f, ps3 = 0.f;
        #pragma unroll
        for (int js = 0; js < 2; js++) {
            #pragma unroll
            for (int r = 0; r < 16; r += 4) {
                float p0 = exp2f(fmaf(sc[js][r + 0], LOG2E, -mL));
                float p1 = exp2f(fmaf(sc[js][r + 1], LOG2E, -mL));
                float p2 = exp2f(fmaf(sc[js][r + 2], LOG2E, -mL));
                float p3 = exp2f(fmaf(sc[js][r + 3], LOG2E, -mL));
                sc[js][r + 0] = p0; sc[js][r + 1] = p1;
                sc[js][r + 2] = p2; sc[js][r + 3] = p3;
                ps0 += p0; ps1 += p1; ps2 += p2; ps3 += p3;
            }
        }
        float ps = (ps0 + ps1) + (ps2 + ps3);
        ps += __shfl_xor(ps, 32);
        lsum += ps;

        // ---- O^T += Vt * P : P fragment built in-register ----
        __builtin_amdgcn_s_setprio(1);
        #pragma unroll
        for (int ks = 0; ks < 4; ks++) {
            int js = ks >> 1, u8 = (ks & 1) * 8;
            PW a0p, a1p, b0p, b1p;
            a0p.h2 = __builtin_amdgcn_cvt_pkrtz(sc[js][u8 + 0], sc[js][u8 + 1]);
            a1p.h2 = __builtin_amdgcn_cvt_pkrtz(sc[js][u8 + 2], sc[js][u8 + 3]);
            b0p.h2 = __builtin_amdgcn_cvt_pkrtz(sc[js][u8 + 4], sc[js][u8 + 5]);
            b1p.h2 = __builtin_amdgcn_cvt_pkrtz(sc[js][u8 + 6], sc[js][u8 + 7]);
            auto r0 = __builtin_amdgcn_permlane32_swap(a0p.u, b0p.u, false, false);
            auto r1 = __builtin_amdgcn_permlane32_swap(a1p.u, b1p.u, false, false);
            union { unsigned int w4[4]; f16x8 f; } pb;
            pb.w4[0] = r0[0]; pb.w4[1] = r1[0];
            pb.w4[2] = r0[1]; pb.w4[3] = r1[1];
            int vb = ks * 2 + hv;
            f16x8 va = *(const f16x8*)&Vb[vb * 256 + (ln ^ vb) * 8];
            O = mfma32h(va, pb.f, O);
        }
        __builtin_amdgcn_s_setprio(0);
    }
#undef STAGE

    // ---- partial epilogue: f16 unnormalized O^T + (m, l) ----
    if (i_glob < NVOX) {
        short* Op = wsO + ((size_t)jp * (B_ * HEADS) + bh) * DK * NVOX;
        #pragma unroll
        for (int r = 0; r < 16; r++) {
            int d = (r & 3) + 8 * (r >> 2) + 4 * hv;
            _Float16 oh = (_Float16)O[r];
            Op[(size_t)d * NVOX + i_glob] = *(short*)&oh;
        }
        if (hv == 0) {
            size_t mo = ((size_t)jp * (B_ * HEADS) + bh) * NVOX + i_glob;
            wsM[mo] = mL;
            wsL[mo] = lsum;
        }
    }
}

// ---------------------------------------------------------------------------
// Combine the three j-third partials (flash merge identity), 4-wide vectorized.
// ---------------------------------------------------------------------------
__global__ void combine_kernel(const short* __restrict__ wsO,
                               const float* __restrict__ wsM,
                               const float* __restrict__ wsL,
                               float* __restrict__ out) {
    int idx = (blockIdx.x * 256 + threadIdx.x) * 4;   // 1,769,472 total
    int i = idx % NVOX;
    int bh = (idx / NVOX) >> 5;
    const size_t oh = (size_t)B_ * HEADS * DK * NVOX;
    const size_t mh = (size_t)B_ * HEADS * NVOX;
    size_t mo = (size_t)bh * NVOX + i;
    float4 m0 = *(const float4*)&wsM[mo];
    float4 m1 = *(const float4*)&wsM[mh + mo];
    float4 m2 = *(const float4*)&wsM[2 * mh + mo];
    float4 l0 = *(const float4*)&wsL[mo];
    float4 l1 = *(const float4*)&wsL[mh + mo];
    float4 l2 = *(const float4*)&wsL[2 * mh + mo];
    uint2 o0u = *(const uint2*)&wsO[idx];
    uint2 o1u = *(const uint2*)&wsO[oh + idx];
    uint2 o2u = *(const uint2*)&wsO[2 * oh + idx];
    const short* o0s = (const short*)&o0u;
    const short* o1s = (const short*)&o1u;
    const short* o2s = (const short*)&o2u;
    const float* m0p = (const float*)&m0; const float* m1p = (const float*)&m1;
    const float* m2p = (const float*)&m2;
    const float* l0p = (const float*)&l0; const float* l1p = (const float*)&l1;
    const float* l2p = (const float*)&l2;
    float4 res;
    float* rp = (float*)&res;
    #pragma unroll
    for (int j = 0; j < 4; j++) {
        float m = fmaxf(fmaxf(m0p[j], m1p[j]), m2p[j]);
        float a0 = exp2f(m0p[j] - m);
        float a1 = exp2f(m1p[j] - m);
        float a2 = exp2f(m2p[j] - m);
        rp[j] = (a0 * h2f(o0s[j]) + a1 * h2f(o1s[j]) + a2 * h2f(o2s[j])) /
                (a0 * l0p[j] + a1 * l1p[j] + a2 * l2p[j]);
    }
    *(float4*)&out[idx] = res;
}

// ---------------------------------------------------------------------------
extern "C" void kernel_launch(void* const* d_in, const int* in_sizes, int n_in,
                              void* d_out, int out_size, void* d_ws, size_t ws_size,
                              hipStream_t stream) {
    const float* x     = (const float*)d_in[0];
    const float* wq    = (const float*)d_in[1];
    const float* bq    = (const float*)d_in[2];
    const float* wk    = (const float*)d_in[3];
    const float* bk    = (const float*)d_in[4];
    const float* wv    = (const float*)d_in[5];
    const float* bv    = (const float*)d_in[6];
    const float* rel_d = (const float*)d_in[7];
    const float* rel_h = (const float*)d_in[8];
    const float* rel_w = (const float*)d_in[9];
    float* out = (float*)d_out;

    size_t qksz = (size_t)B_ * HEADS * NVOX * DE;        // 3,538,944
    size_t vsz  = (size_t)B_ * HEADS * DK * NVOX;        // 1,769,472
    short* Qf  = (short*)d_ws;
    short* Kf  = Qf + qksz;                              // 32-wide: vsz shorts
    short* Vf  = Kf + vsz;
    short* wf  = Vf + vsz;                               // 196,608 shorts
    short* wsO = wf + (size_t)3 * C_ * C_;               // 3*vsz shorts (f16)
    float* wsM = (float*)(wsO + 3 * vsz);                // 3*B*H*NVOX floats
    float* wsL = wsM + 3 * (size_t)B_ * HEADS * NVOX;
    short* xf  = wsO;                                    // aliases wsO (dead before attn)

    prep_kernel<<<dim3(1488), dim3(256), 0, stream>>>(
        x, wq, wk, wv, rel_d, rel_h, rel_w, wf, xf, Qf);
    fproj_kernel<<<dim3(NVOX / 64, HEADS, B_), dim3(384), 0, stream>>>(
        xf, wf, bq, bk, bv, Qf, Kf, Vf);
    attn_kernel<<<dim3(ITILES * JSPLIT * HEADS * B_), dim3(256), 0, stream>>>(
        Qf, Kf, Vf, wsO, wsM, wsL);
    combine_kernel<<<dim3((int)(vsz / 1024)), dim3(256), 0, stream>>>(wsO, wsM, wsL, out);
}